// Round 1
// baseline (661.081 us; speedup 1.0000x reference)
//
#include <hip/hip_runtime.h>
#include <hip/hip_bf16.h>
#include <cstdint>

#define SEQ   8192
#define DIN   4096
#define DOUT  4096
#define RANK  16
#define NAD   8
#define KC    (DIN + NAD*RANK)   /* 4224 concatenated K */

using f32x4  = __attribute__((ext_vector_type(4))) float;
using bf16x8 = __attribute__((ext_vector_type(8))) short;   // 8 bf16 in 4 VGPRs

// fp32 -> bf16 round-to-nearest-even (inputs finite)
__device__ __forceinline__ unsigned short f2bf(float f) {
  union { float f; uint32_t u; } v; v.f = f;
  return (unsigned short)((v.u + 0x7fffu + ((v.u >> 16) & 1u)) >> 16);
}

// async global->LDS direct copy, 16B per lane (wave-uniform LDS base + lane*16)
__device__ __forceinline__ void async_copy16(void* lds, const void* gmem) {
  __builtin_amdgcn_global_load_lds(
      (__attribute__((address_space(1))) void*)(uintptr_t)gmem,
      (__attribute__((address_space(3))) void*)(uint32_t)(uintptr_t)lds,
      16, 0, 0);
}

// ---------------- conversion kernels ----------------

// x fp32 [SEQ][DIN] -> xcat bf16 rows of stride KC, cols 0..DIN-1
__global__ void cvt_x_kernel(const float* __restrict__ x, unsigned short* __restrict__ xcat) {
  const int64_t nchunks = (int64_t)SEQ * DIN / 8;
  for (int64_t c = (int64_t)blockIdx.x * blockDim.x + threadIdx.x; c < nchunks;
       c += (int64_t)gridDim.x * blockDim.x) {
    int64_t base = c * 8;
    int s = (int)(base >> 12);        // /DIN
    int k = (int)(base & (DIN - 1));
    float4 p = *(const float4*)(x + base);
    float4 q = *(const float4*)(x + base + 4);
    union { unsigned short h[8]; int4 v; } o;
    o.h[0]=f2bf(p.x); o.h[1]=f2bf(p.y); o.h[2]=f2bf(p.z); o.h[3]=f2bf(p.w);
    o.h[4]=f2bf(q.x); o.h[5]=f2bf(q.y); o.h[6]=f2bf(q.z); o.h[7]=f2bf(q.w);
    *(int4*)(xcat + (int64_t)s * KC + k) = o.v;
  }
}

// A_buffer fp32 [NAD*RANK][DIN] -> abf bf16 [128][DIN] (contiguous)
__global__ void cvt_a_kernel(const float* __restrict__ a, unsigned short* __restrict__ abf) {
  int c = blockIdx.x * 256 + threadIdx.x;     // 65536 chunks of 8
  int64_t base = (int64_t)c * 8;
  float4 p = *(const float4*)(a + base);
  float4 q = *(const float4*)(a + base + 4);
  union { unsigned short h[8]; int4 v; } o;
  o.h[0]=f2bf(p.x); o.h[1]=f2bf(p.y); o.h[2]=f2bf(p.z); o.h[3]=f2bf(p.w);
  o.h[4]=f2bf(q.x); o.h[5]=f2bf(q.y); o.h[6]=f2bf(q.z); o.h[7]=f2bf(q.w);
  *(int4*)(abf + base) = o.v;
}

// weight fp32 [DIN(k)][DOUT(n)] -> wcat bf16 [n][k] stride KC (transpose via LDS tile)
__global__ void cvt_w_kernel(const float* __restrict__ w, unsigned short* __restrict__ wcat) {
  __shared__ float tile[32][33];
  int bk = blockIdx.x & 127;   // k-tile
  int bn = blockIdx.x >> 7;    // n-tile
  int k0 = bk * 32, n0 = bn * 32;
  int tn  = threadIdx.x & 31;
  int tg  = threadIdx.x >> 5;  // 0..7
#pragma unroll
  for (int i = 0; i < 4; i++) {
    int k = tg * 4 + i;
    tile[k][tn] = w[(int64_t)(k0 + k) * DOUT + n0 + tn];
  }
  __syncthreads();
#pragma unroll
  for (int i = 0; i < 4; i++) {
    int n = tg * 4 + i;
    wcat[(int64_t)(n0 + n) * KC + k0 + tn] = f2bf(tile[tn][n]);
  }
}

// B_buffer fp32 [NAD][DOUT][RANK] -> wcat[n][DIN + e*16 + r]
__global__ void cvt_b_kernel(const float* __restrict__ Bbuf, unsigned short* __restrict__ wcat) {
  int idx = blockIdx.x * 256 + threadIdx.x;  // n*128 + er
  int n = idx >> 7, er = idx & 127;
  int e = er >> 4, r = er & 15;
  float v = Bbuf[((int64_t)e * DOUT + n) * RANK + r];
  wcat[(int64_t)n * KC + DIN + er] = f2bf(v);
}

// ---------------- LoRA-A projection GEMM ----------------
// a_masked[s][er] = (x[s]·A[e][r]) * scal[s] * (tok[s]==e) -> bf16 into xcat cols DIN..DIN+127
// M=SEQ (BM=32/block), N=128, K=DIN. Reads xcat cols < DIN, writes cols >= DIN (disjoint).
__global__ __launch_bounds__(256) void gemm_lora_a(
    const unsigned short* A,            // xcat, stride KC
    const unsigned short* __restrict__ Bb, // abf [128][DIN]
    const float* __restrict__ scal,
    const int* __restrict__ tok,
    unsigned short* xcat_out) {
  constexpr int BK = 32;
  __shared__ unsigned short sA[32 * BK];
  __shared__ unsigned short sB[128 * BK];
  int tid = threadIdx.x, wave = tid >> 6, lane = tid & 63;
  int quad = lane >> 4, l16 = lane & 15;
  int row0 = blockIdx.x * 32;

  const f32x4 zero = {0.f, 0.f, 0.f, 0.f};
  f32x4 acc[2][2];
  acc[0][0] = zero; acc[0][1] = zero; acc[1][0] = zero; acc[1][1] = zero;

  for (int kt = 0; kt < DIN / BK; ++kt) {
    int k0 = kt * BK;
    if (wave < 2) {                       // A tile: 32x32 = 128 chunks
      int c = wave * 64 + lane;
      int r = c >> 2, kc = (c & 3) * 8;
      async_copy16(&sA[c * 8], A + (int64_t)(row0 + r) * KC + k0 + kc);
    }
#pragma unroll
    for (int i = 0; i < 2; i++) {         // B tile: 128x32 = 512 chunks
      int c = i * 256 + tid;
      int r = c >> 2, kc = (c & 3) * 8;
      async_copy16(&sB[c * 8], Bb + (int64_t)r * DIN + k0 + kc);
    }
    __syncthreads();
    bf16x8 af[2], bfr[2];
#pragma unroll
    for (int mi = 0; mi < 2; mi++)
      af[mi] = *(const bf16x8*)&sA[(mi * 16 + l16) * BK + quad * 8];
#pragma unroll
    for (int ni = 0; ni < 2; ni++)
      bfr[ni] = *(const bf16x8*)&sB[(wave * 32 + ni * 16 + l16) * BK + quad * 8];
#pragma unroll
    for (int mi = 0; mi < 2; mi++)
#pragma unroll
      for (int ni = 0; ni < 2; ni++)
        acc[mi][ni] = __builtin_amdgcn_mfma_f32_16x16x32_bf16(af[mi], bfr[ni], acc[mi][ni], 0, 0, 0);
    __syncthreads();
  }

#pragma unroll
  for (int ni = 0; ni < 2; ni++) {
    int er = wave * 32 + ni * 16 + l16;
    int e  = er >> 4;
#pragma unroll
    for (int mi = 0; mi < 2; mi++) {
#pragma unroll
      for (int r = 0; r < 4; r++) {
        int s = row0 + mi * 16 + quad * 4 + r;
        float v = acc[mi][ni][r] * scal[s];
        v = (tok[s] == e) ? v : 0.0f;
        xcat_out[(int64_t)s * KC + DIN + er] = f2bf(v);
      }
    }
  }
}

// ---------------- main GEMM ----------------
// out[s][n] = sum_k xcat[s][k]*wcat[n][k] + bias[n], K=KC=4224 (base + LoRA folded in)
__global__ __launch_bounds__(256) void gemm_main(
    const unsigned short* __restrict__ A,   // xcat [SEQ][KC]
    const unsigned short* __restrict__ B,   // wcat [DOUT][KC]
    const float* __restrict__ bias,
    float* __restrict__ out) {
  constexpr int BK = 32;
  constexpr int KITERS = KC / BK;           // 132
  __shared__ unsigned short sA[128 * BK];
  __shared__ unsigned short sB[128 * BK];
  int tid = threadIdx.x, wave = tid >> 6, lane = tid & 63;
  int quad = lane >> 4, l16 = lane & 15;
  int bn = blockIdx.x & 31, bm = blockIdx.x >> 5;
  int row0 = bm * 128, col0 = bn * 128;
  int wm = wave >> 1, wn = wave & 1;        // 2x2 waves of 64x64

  const f32x4 zero = {0.f, 0.f, 0.f, 0.f};
  f32x4 acc[4][4];
#pragma unroll
  for (int i = 0; i < 4; i++)
#pragma unroll
    for (int j = 0; j < 4; j++) acc[i][j] = zero;

  const unsigned short* Ab = A + (int64_t)row0 * KC;
  const unsigned short* Bb = B + (int64_t)col0 * KC;

  for (int kt = 0; kt < KITERS; ++kt) {
    int k0 = kt * BK;
#pragma unroll
    for (int i = 0; i < 2; i++) {           // 2x A + 2x B staging insts
      int c = i * 256 + tid;
      int r = c >> 2, kc = (c & 3) * 8;
      async_copy16(&sA[c * 8], Ab + (int64_t)r * KC + k0 + kc);
      async_copy16(&sB[c * 8], Bb + (int64_t)r * KC + k0 + kc);
    }
    __syncthreads();
    bf16x8 af[4], bfr[4];
#pragma unroll
    for (int mi = 0; mi < 4; mi++)
      af[mi] = *(const bf16x8*)&sA[(wm * 64 + mi * 16 + l16) * BK + quad * 8];
#pragma unroll
    for (int ni = 0; ni < 4; ni++)
      bfr[ni] = *(const bf16x8*)&sB[(wn * 64 + ni * 16 + l16) * BK + quad * 8];
#pragma unroll
    for (int mi = 0; mi < 4; mi++)
#pragma unroll
      for (int ni = 0; ni < 4; ni++)
        acc[mi][ni] = __builtin_amdgcn_mfma_f32_16x16x32_bf16(af[mi], bfr[ni], acc[mi][ni], 0, 0, 0);
    __syncthreads();
  }

#pragma unroll
  for (int ni = 0; ni < 4; ni++) {
    int col = col0 + wn * 64 + ni * 16 + l16;
    float bv = bias[col];
#pragma unroll
    for (int mi = 0; mi < 4; mi++) {
      int rbase = row0 + wm * 64 + mi * 16 + quad * 4;
#pragma unroll
      for (int r = 0; r < 4; r++)
        out[(int64_t)(rbase + r) * DOUT + col] = acc[mi][ni][r] + bv;
    }
  }
}

// ---------------- slow fp32 fallback (ws too small insurance) ----------------
__global__ void fb_aout(const float* __restrict__ x, const float* __restrict__ Abuf,
                        const float* __restrict__ scal, const int* __restrict__ tok,
                        float* __restrict__ aout) {
  int s = blockIdx.x;
  int e = tok[s];
  __shared__ float red[256];
  for (int r = 0; r < RANK; ++r) {
    float p = 0.f;
    for (int k = threadIdx.x; k < DIN; k += 256)
      p += x[(int64_t)s * DIN + k] * Abuf[((int64_t)e * RANK + r) * DIN + k];
    red[threadIdx.x] = p;
    __syncthreads();
    for (int off = 128; off > 0; off >>= 1) {
      if (threadIdx.x < off) red[threadIdx.x] += red[threadIdx.x + off];
      __syncthreads();
    }
    if (threadIdx.x == 0) aout[s * RANK + r] = red[0] * scal[s];
    __syncthreads();
  }
}
__global__ void fb_out(const float* __restrict__ x, const float* __restrict__ w,
                       const float* __restrict__ bias, const float* __restrict__ Bbuf,
                       const int* __restrict__ tok, const float* __restrict__ aout,
                       float* __restrict__ out) {
  int64_t idx = (int64_t)blockIdx.x * blockDim.x + threadIdx.x;
  int s = (int)(idx >> 12), n = (int)(idx & (DOUT - 1));
  float accv = bias[n];
  for (int k = 0; k < DIN; ++k)
    accv += x[(int64_t)s * DIN + k] * w[(int64_t)k * DOUT + n];
  int e = tok[s];
  float d = 0.f;
  for (int r = 0; r < RANK; ++r)
    d += aout[s * RANK + r] * Bbuf[((int64_t)e * DOUT + n) * RANK + r];
  out[idx] = accv + d;
}

extern "C" void kernel_launch(void* const* d_in, const int* in_sizes, int n_in,
                              void* d_out, int out_size, void* d_ws, size_t ws_size,
                              hipStream_t stream) {
  const float* x    = (const float*)d_in[0];
  const float* w    = (const float*)d_in[1];
  const float* bias = (const float*)d_in[2];
  const float* Abuf = (const float*)d_in[3];
  const float* Bbuf = (const float*)d_in[4];
  const float* scal = (const float*)d_in[5];
  const int*   tok  = (const int*)d_in[6];
  float* out = (float*)d_out;

  const size_t xcat_b = (size_t)SEQ * KC * 2;        // 69,206,016 B
  const size_t wcat_b = (size_t)DOUT * KC * 2;       // 34,603,008 B
  const size_t abf_b  = (size_t)NAD * RANK * DIN * 2;//  1,048,576 B

  if (ws_size >= xcat_b + wcat_b + abf_b) {
    unsigned short* xcat = (unsigned short*)d_ws;
    unsigned short* wcat = (unsigned short*)((char*)d_ws + xcat_b);
    unsigned short* abf  = (unsigned short*)((char*)d_ws + xcat_b + wcat_b);
    cvt_x_kernel<<<4096, 256, 0, stream>>>(x, xcat);
    cvt_w_kernel<<<16384, 256, 0, stream>>>(w, wcat);
    cvt_b_kernel<<<(DOUT * 128) / 256, 256, 0, stream>>>(Bbuf, wcat);
    cvt_a_kernel<<<(NAD * RANK * DIN / 8) / 256, 256, 0, stream>>>(Abuf, abf);
    gemm_lora_a<<<SEQ / 32, 256, 0, stream>>>(xcat, abf, scal, tok, xcat);
    gemm_main<<<(SEQ / 128) * (DOUT / 128), 256, 0, stream>>>(xcat, wcat, bias, out);
  } else {
    float* aout = (float*)d_ws;  // needs 512 KB
    fb_aout<<<SEQ, 256, 0, stream>>>(x, Abuf, scal, tok, aout);
    fb_out<<<(int)(((int64_t)SEQ * DOUT) / 256), 256, 0, stream>>>(x, w, bias, Bbuf, tok, aout, out);
  }
}

// Round 2
// 656.116 us; speedup vs baseline: 1.0076x; 1.0076x over previous
//
#include <hip/hip_runtime.h>
#include <hip/hip_bf16.h>
#include <cstdint>

#define SEQ   8192
#define DIN   4096
#define DOUT  4096
#define RANK  16
#define NAD   8
#define KC    (DIN + NAD*RANK)   /* 4224 concatenated K */

using f32x4  = __attribute__((ext_vector_type(4))) float;
using bf16x8 = __attribute__((ext_vector_type(8))) short;   // 8 bf16 in 4 VGPRs

// fp32 -> bf16 round-to-nearest-even (inputs finite)
__device__ __forceinline__ unsigned short f2bf(float f) {
  union { float f; uint32_t u; } v; v.f = f;
  return (unsigned short)((v.u + 0x7fffu + ((v.u >> 16) & 1u)) >> 16);
}

// async global->LDS direct copy, 16B per lane (wave-uniform LDS base + lane*16)
__device__ __forceinline__ void async_copy16(void* lds, const void* gmem) {
  __builtin_amdgcn_global_load_lds(
      (__attribute__((address_space(1))) void*)(uintptr_t)gmem,
      (__attribute__((address_space(3))) void*)(uint32_t)(uintptr_t)lds,
      16, 0, 0);
}

// ---------------- conversion kernels ----------------

// x fp32 [SEQ][DIN] -> xcat bf16 rows of stride KC, cols 0..DIN-1
__global__ void cvt_x_kernel(const float* __restrict__ x, unsigned short* __restrict__ xcat) {
  const int64_t nchunks = (int64_t)SEQ * DIN / 8;
  for (int64_t c = (int64_t)blockIdx.x * blockDim.x + threadIdx.x; c < nchunks;
       c += (int64_t)gridDim.x * blockDim.x) {
    int64_t base = c * 8;
    int s = (int)(base >> 12);        // /DIN
    int k = (int)(base & (DIN - 1));
    float4 p = *(const float4*)(x + base);
    float4 q = *(const float4*)(x + base + 4);
    union { unsigned short h[8]; int4 v; } o;
    o.h[0]=f2bf(p.x); o.h[1]=f2bf(p.y); o.h[2]=f2bf(p.z); o.h[3]=f2bf(p.w);
    o.h[4]=f2bf(q.x); o.h[5]=f2bf(q.y); o.h[6]=f2bf(q.z); o.h[7]=f2bf(q.w);
    *(int4*)(xcat + (int64_t)s * KC + k) = o.v;
  }
}

// A_buffer fp32 [NAD*RANK][DIN] -> abf bf16 [128][DIN] (contiguous)
__global__ void cvt_a_kernel(const float* __restrict__ a, unsigned short* __restrict__ abf) {
  int c = blockIdx.x * 256 + threadIdx.x;     // 65536 chunks of 8
  int64_t base = (int64_t)c * 8;
  float4 p = *(const float4*)(a + base);
  float4 q = *(const float4*)(a + base + 4);
  union { unsigned short h[8]; int4 v; } o;
  o.h[0]=f2bf(p.x); o.h[1]=f2bf(p.y); o.h[2]=f2bf(p.z); o.h[3]=f2bf(p.w);
  o.h[4]=f2bf(q.x); o.h[5]=f2bf(q.y); o.h[6]=f2bf(q.z); o.h[7]=f2bf(q.w);
  *(int4*)(abf + base) = o.v;
}

// weight fp32 [DIN(k)][DOUT(n)] -> wcat bf16 [n][k] stride KC.
// LDS-free transpose: each thread reads 8 column elements (coalesced across
// lanes: consecutive n per load instruction) and writes one int4 (8 bf16 along k).
// Block covers 32 n x 64 k; grid = 128 n-tiles * 64 k-tiles = 8192 blocks.
__global__ void cvt_w_kernel(const float* __restrict__ w, unsigned short* __restrict__ wcat) {
  int t  = threadIdx.x;
  int bn = blockIdx.x & 127;
  int bk = blockIdx.x >> 7;
  int n = bn * 32 + (t & 31);
  int k = bk * 64 + (t >> 5) * 8;
  union { unsigned short h[8]; int4 v; } o;
#pragma unroll
  for (int j = 0; j < 8; j++)
    o.h[j] = f2bf(w[(int64_t)(k + j) * DOUT + n]);
  *(int4*)(wcat + (int64_t)n * KC + k) = o.v;
}

// B_buffer fp32 [NAD][DOUT][RANK] -> wcat[n][DIN + e*16 + r]
__global__ void cvt_b_kernel(const float* __restrict__ Bbuf, unsigned short* __restrict__ wcat) {
  int idx = blockIdx.x * 256 + threadIdx.x;  // n*128 + er
  int n = idx >> 7, er = idx & 127;
  int e = er >> 4, r = er & 15;
  float v = Bbuf[((int64_t)e * DOUT + n) * RANK + r];
  wcat[(int64_t)n * KC + DIN + er] = f2bf(v);
}

// ---------------- LoRA-A projection GEMM (K-split, fp32 partials) ----------------
// aout[sp][s][er] = sum over K-range sp of xcat[s][k]*abf[er][k]
// BM=64, BN=128, BK=64, splits=2 -> grid 256 blocks, 32 K-iters each.
__global__ __launch_bounds__(256) void gemm_lora_a(
    const unsigned short* __restrict__ A,   // xcat
    const unsigned short* __restrict__ Bb,  // abf [128][DIN]
    float* __restrict__ aout) {             // [2][SEQ][128]
  constexpr int BK = 64;
  __shared__ unsigned short sA[64 * BK];    //  8 KB
  __shared__ unsigned short sB[128 * BK];   // 16 KB
  int tid = threadIdx.x, wave = tid >> 6, lane = tid & 63;
  int quad = lane >> 4, l16 = lane & 15;
  int mb = blockIdx.x & 127;                // 128 m-blocks
  int sp = blockIdx.x >> 7;                 // 2 K-splits
  int row0 = mb * 64;
  int kbase = sp * (DIN / 2);
  int wm = wave >> 1, wn = wave & 1;        // wave tile 32m x 64n

  const f32x4 zero = {0.f, 0.f, 0.f, 0.f};
  f32x4 acc[2][4];
#pragma unroll
  for (int i = 0; i < 2; i++)
#pragma unroll
    for (int j = 0; j < 4; j++) acc[i][j] = zero;

  for (int kt = 0; kt < (DIN / 2) / BK; ++kt) {   // 32 iters
    int k0 = kbase + kt * BK;
#pragma unroll
    for (int i = 0; i < 2; i++) {            // A tile: 64x64 = 512 chunks
      int c = i * 256 + tid;
      int r = c >> 3, kc = (c & 7) * 8;
      async_copy16(&sA[c * 8], A + (int64_t)(row0 + r) * KC + k0 + kc);
    }
#pragma unroll
    for (int i = 0; i < 4; i++) {            // B tile: 128x64 = 1024 chunks
      int c = i * 256 + tid;
      int r = c >> 3, kc = (c & 7) * 8;
      async_copy16(&sB[c * 8], Bb + (int64_t)r * DIN + k0 + kc);
    }
    __syncthreads();
#pragma unroll
    for (int ks = 0; ks < 2; ks++) {
      bf16x8 af[2], bfr[4];
#pragma unroll
      for (int mi = 0; mi < 2; mi++)
        af[mi] = *(const bf16x8*)&sA[(wm * 32 + mi * 16 + l16) * BK + ks * 32 + quad * 8];
#pragma unroll
      for (int ni = 0; ni < 4; ni++)
        bfr[ni] = *(const bf16x8*)&sB[(wn * 64 + ni * 16 + l16) * BK + ks * 32 + quad * 8];
#pragma unroll
      for (int mi = 0; mi < 2; mi++)
#pragma unroll
        for (int ni = 0; ni < 4; ni++)
          acc[mi][ni] = __builtin_amdgcn_mfma_f32_16x16x32_bf16(af[mi], bfr[ni], acc[mi][ni], 0, 0, 0);
    }
    __syncthreads();
  }

  float* op = aout + (int64_t)sp * SEQ * 128;
#pragma unroll
  for (int ni = 0; ni < 4; ni++) {
    int er = wn * 64 + ni * 16 + l16;
#pragma unroll
    for (int mi = 0; mi < 2; mi++) {
      int s0 = row0 + wm * 32 + mi * 16 + quad * 4;
#pragma unroll
      for (int r = 0; r < 4; r++)
        op[(int64_t)(s0 + r) * 128 + er] = acc[mi][ni][r];
    }
  }
}

// sum splits, scale, mask, write bf16 LoRA columns of xcat
__global__ void lora_combine(const float* __restrict__ aout, const float* __restrict__ scal,
                             const int* __restrict__ tok, unsigned short* __restrict__ xcat) {
  int idx = blockIdx.x * 256 + threadIdx.x;   // s*128 + er, 1M total
  int s = idx >> 7, er = idx & 127;
  float v = aout[idx] + aout[idx + (int64_t)SEQ * 128];
  v *= scal[s];
  v = ((er >> 4) == tok[s]) ? v : 0.0f;
  xcat[(int64_t)s * KC + DIN + er] = f2bf(v);
}

// ---------------- main GEMM ----------------
// out[s][n] = sum_k xcat[s][k]*wcat[n][k] + bias[n], K=KC=4224 (base + LoRA folded in)
__global__ __launch_bounds__(256) void gemm_main(
    const unsigned short* __restrict__ A,   // xcat [SEQ][KC]
    const unsigned short* __restrict__ B,   // wcat [DOUT][KC]
    const float* __restrict__ bias,
    float* __restrict__ out) {
  constexpr int BK = 32;
  constexpr int KITERS = KC / BK;           // 132
  __shared__ unsigned short sA[128 * BK];
  __shared__ unsigned short sB[128 * BK];
  int tid = threadIdx.x, wave = tid >> 6, lane = tid & 63;
  int quad = lane >> 4, l16 = lane & 15;
  int bn = blockIdx.x & 31, bm = blockIdx.x >> 5;
  int row0 = bm * 128, col0 = bn * 128;
  int wm = wave >> 1, wn = wave & 1;        // 2x2 waves of 64x64

  const f32x4 zero = {0.f, 0.f, 0.f, 0.f};
  f32x4 acc[4][4];
#pragma unroll
  for (int i = 0; i < 4; i++)
#pragma unroll
    for (int j = 0; j < 4; j++) acc[i][j] = zero;

  const unsigned short* Ab = A + (int64_t)row0 * KC;
  const unsigned short* Bb = B + (int64_t)col0 * KC;

  for (int kt = 0; kt < KITERS; ++kt) {
    int k0 = kt * BK;
#pragma unroll
    for (int i = 0; i < 2; i++) {           // 2x A + 2x B staging insts
      int c = i * 256 + tid;
      int r = c >> 2, kc = (c & 3) * 8;
      async_copy16(&sA[c * 8], Ab + (int64_t)r * KC + k0 + kc);
      async_copy16(&sB[c * 8], Bb + (int64_t)r * KC + k0 + kc);
    }
    __syncthreads();
    bf16x8 af[4], bfr[4];
#pragma unroll
    for (int mi = 0; mi < 4; mi++)
      af[mi] = *(const bf16x8*)&sA[(wm * 64 + mi * 16 + l16) * BK + quad * 8];
#pragma unroll
    for (int ni = 0; ni < 4; ni++)
      bfr[ni] = *(const bf16x8*)&sB[(wn * 64 + ni * 16 + l16) * BK + quad * 8];
#pragma unroll
    for (int mi = 0; mi < 4; mi++)
#pragma unroll
      for (int ni = 0; ni < 4; ni++)
        acc[mi][ni] = __builtin_amdgcn_mfma_f32_16x16x32_bf16(af[mi], bfr[ni], acc[mi][ni], 0, 0, 0);
    __syncthreads();
  }

#pragma unroll
  for (int ni = 0; ni < 4; ni++) {
    int col = col0 + wn * 64 + ni * 16 + l16;
    float bv = bias[col];
#pragma unroll
    for (int mi = 0; mi < 4; mi++) {
      int rbase = row0 + wm * 64 + mi * 16 + quad * 4;
#pragma unroll
      for (int r = 0; r < 4; r++)
        out[(int64_t)(rbase + r) * DOUT + col] = acc[mi][ni][r] + bv;
    }
  }
}

// ---------------- slow fp32 fallback (ws too small insurance) ----------------
__global__ void fb_aout(const float* __restrict__ x, const float* __restrict__ Abuf,
                        const float* __restrict__ scal, const int* __restrict__ tok,
                        float* __restrict__ aout) {
  int s = blockIdx.x;
  int e = tok[s];
  __shared__ float red[256];
  for (int r = 0; r < RANK; ++r) {
    float p = 0.f;
    for (int k = threadIdx.x; k < DIN; k += 256)
      p += x[(int64_t)s * DIN + k] * Abuf[((int64_t)e * RANK + r) * DIN + k];
    red[threadIdx.x] = p;
    __syncthreads();
    for (int off = 128; off > 0; off >>= 1) {
      if (threadIdx.x < off) red[threadIdx.x] += red[threadIdx.x + off];
      __syncthreads();
    }
    if (threadIdx.x == 0) aout[s * RANK + r] = red[0] * scal[s];
    __syncthreads();
  }
}
__global__ void fb_out(const float* __restrict__ x, const float* __restrict__ w,
                       const float* __restrict__ bias, const float* __restrict__ Bbuf,
                       const int* __restrict__ tok, const float* __restrict__ aout,
                       float* __restrict__ out) {
  int64_t idx = (int64_t)blockIdx.x * blockDim.x + threadIdx.x;
  int s = (int)(idx >> 12), n = (int)(idx & (DOUT - 1));
  float accv = bias[n];
  for (int k = 0; k < DIN; ++k)
    accv += x[(int64_t)s * DIN + k] * w[(int64_t)k * DOUT + n];
  int e = tok[s];
  float d = 0.f;
  for (int r = 0; r < RANK; ++r)
    d += aout[s * RANK + r] * Bbuf[((int64_t)e * DOUT + n) * RANK + r];
  out[idx] = accv + d;
}

extern "C" void kernel_launch(void* const* d_in, const int* in_sizes, int n_in,
                              void* d_out, int out_size, void* d_ws, size_t ws_size,
                              hipStream_t stream) {
  const float* x    = (const float*)d_in[0];
  const float* w    = (const float*)d_in[1];
  const float* bias = (const float*)d_in[2];
  const float* Abuf = (const float*)d_in[3];
  const float* Bbuf = (const float*)d_in[4];
  const float* scal = (const float*)d_in[5];
  const int*   tok  = (const int*)d_in[6];
  float* out = (float*)d_out;

  const size_t xcat_b = (size_t)SEQ * KC * 2;          // 69,206,016 B
  const size_t wcat_b = (size_t)DOUT * KC * 2;         // 34,603,008 B
  const size_t abf_b  = (size_t)NAD * RANK * DIN * 2;  //  1,048,576 B
  const size_t aout_b = (size_t)2 * SEQ * 128 * 4;     //  8,388,608 B

  if (ws_size >= xcat_b + wcat_b + abf_b + aout_b) {
    unsigned short* xcat = (unsigned short*)d_ws;
    unsigned short* wcat = (unsigned short*)((char*)d_ws + xcat_b);
    unsigned short* abf  = (unsigned short*)((char*)d_ws + xcat_b + wcat_b);
    float*          aout = (float*)((char*)d_ws + xcat_b + wcat_b + abf_b);
    cvt_x_kernel<<<4096, 256, 0, stream>>>(x, xcat);
    cvt_w_kernel<<<8192, 256, 0, stream>>>(w, wcat);
    cvt_b_kernel<<<(DOUT * 128) / 256, 256, 0, stream>>>(Bbuf, wcat);
    cvt_a_kernel<<<(NAD * RANK * DIN / 8) / 256, 256, 0, stream>>>(Abuf, abf);
    gemm_lora_a<<<256, 256, 0, stream>>>(xcat, abf, aout);
    lora_combine<<<(SEQ * 128) / 256, 256, 0, stream>>>(aout, scal, tok, xcat);
    gemm_main<<<(SEQ / 128) * (DOUT / 128), 256, 0, stream>>>(xcat, wcat, bias, out);
  } else {
    float* aout = (float*)d_ws;  // needs 512 KB
    fb_aout<<<SEQ, 256, 0, stream>>>(x, Abuf, scal, tok, aout);
    fb_out<<<(int)(((int64_t)SEQ * DOUT) / 256), 256, 0, stream>>>(x, w, bias, Bbuf, tok, aout, out);
  }
}

// Round 3
// 636.207 us; speedup vs baseline: 1.0391x; 1.0313x over previous
//
#include <hip/hip_runtime.h>
#include <hip/hip_bf16.h>
#include <cstdint>

#define SEQ   8192
#define DIN   4096
#define DOUT  4096
#define RANK  16
#define NAD   8
#define KC    (DIN + NAD*RANK)   /* 4224 concatenated K */

using f32x4  = __attribute__((ext_vector_type(4))) float;
using bf16x8 = __attribute__((ext_vector_type(8))) short;   // 8 bf16 in 4 VGPRs

// fp32 -> bf16 round-to-nearest-even (inputs finite)
__device__ __forceinline__ unsigned short f2bf(float f) {
  union { float f; uint32_t u; } v; v.f = f;
  return (unsigned short)((v.u + 0x7fffu + ((v.u >> 16) & 1u)) >> 16);
}

// async global->LDS direct copy, 16B per lane (wave-uniform LDS base + lane*16)
__device__ __forceinline__ void async_copy16(void* lds, const void* gmem) {
  __builtin_amdgcn_global_load_lds(
      (__attribute__((address_space(1))) void*)(uintptr_t)gmem,
      (__attribute__((address_space(3))) void*)(uint32_t)(uintptr_t)lds,
      16, 0, 0);
}

// ---------------- conversion kernels ----------------

// x fp32 [SEQ][DIN] -> xcat bf16 rows of stride KC, cols 0..DIN-1
__global__ void cvt_x_kernel(const float* __restrict__ x, unsigned short* __restrict__ xcat) {
  const int64_t nchunks = (int64_t)SEQ * DIN / 8;
  for (int64_t c = (int64_t)blockIdx.x * blockDim.x + threadIdx.x; c < nchunks;
       c += (int64_t)gridDim.x * blockDim.x) {
    int64_t base = c * 8;
    int s = (int)(base >> 12);        // /DIN
    int k = (int)(base & (DIN - 1));
    float4 p = *(const float4*)(x + base);
    float4 q = *(const float4*)(x + base + 4);
    union { unsigned short h[8]; int4 v; } o;
    o.h[0]=f2bf(p.x); o.h[1]=f2bf(p.y); o.h[2]=f2bf(p.z); o.h[3]=f2bf(p.w);
    o.h[4]=f2bf(q.x); o.h[5]=f2bf(q.y); o.h[6]=f2bf(q.z); o.h[7]=f2bf(q.w);
    *(int4*)(xcat + (int64_t)s * KC + k) = o.v;
  }
}

// A_buffer fp32 [NAD*RANK][DIN] -> abf bf16 [128][DIN] (contiguous)
__global__ void cvt_a_kernel(const float* __restrict__ a, unsigned short* __restrict__ abf) {
  int c = blockIdx.x * 256 + threadIdx.x;     // 65536 chunks of 8
  int64_t base = (int64_t)c * 8;
  float4 p = *(const float4*)(a + base);
  float4 q = *(const float4*)(a + base + 4);
  union { unsigned short h[8]; int4 v; } o;
  o.h[0]=f2bf(p.x); o.h[1]=f2bf(p.y); o.h[2]=f2bf(p.z); o.h[3]=f2bf(p.w);
  o.h[4]=f2bf(q.x); o.h[5]=f2bf(q.y); o.h[6]=f2bf(q.z); o.h[7]=f2bf(q.w);
  *(int4*)(abf + base) = o.v;
}

// weight fp32 [DIN(k)][DOUT(n)] -> wcat bf16 [n][k] stride KC.
// LDS-free transpose: coalesced column reads (lane-consecutive n), one int4
// (8 bf16 along k) store per thread. Block = 32n x 64k.
__global__ void cvt_w_kernel(const float* __restrict__ w, unsigned short* __restrict__ wcat) {
  int t  = threadIdx.x;
  int bn = blockIdx.x & 127;
  int bk = blockIdx.x >> 7;
  int n = bn * 32 + (t & 31);
  int k = bk * 64 + (t >> 5) * 8;
  union { unsigned short h[8]; int4 v; } o;
#pragma unroll
  for (int j = 0; j < 8; j++)
    o.h[j] = f2bf(w[(int64_t)(k + j) * DOUT + n]);
  *(int4*)(wcat + (int64_t)n * KC + k) = o.v;
}

// B_buffer fp32 [NAD][DOUT][RANK] -> wcat[n][DIN + e*16 + r]
__global__ void cvt_b_kernel(const float* __restrict__ Bbuf, unsigned short* __restrict__ wcat) {
  int idx = blockIdx.x * 256 + threadIdx.x;  // n*128 + er
  int n = idx >> 7, er = idx & 127;
  int e = er >> 4, r = er & 15;
  float v = Bbuf[((int64_t)e * DOUT + n) * RANK + r];
  wcat[(int64_t)n * KC + DIN + er] = f2bf(v);
}

// ---------------- LoRA-A projection GEMM (K-split, fp32 partials) ----------------
// aout[sp][s][er] = sum over K-range sp of xcat[s][k]*abf[er][k]
// BM=64, BN=128, BK=64, splits=2 -> grid 256 blocks, 32 K-iters each.
// LDS layout XOR-swizzled: slot (r, qp) holds gmem 16B-quarter (qp ^ (r&7));
// 128B rows -> bank = quarter index -> fragment reads fully conflict-free.
__global__ __launch_bounds__(256) void gemm_lora_a(
    const unsigned short* __restrict__ A,   // xcat
    const unsigned short* __restrict__ Bb,  // abf [128][DIN]
    float* __restrict__ aout) {             // [2][SEQ][128]
  constexpr int BK = 64;
  __shared__ unsigned short sA[64 * BK];    //  8 KB
  __shared__ unsigned short sB[128 * BK];   // 16 KB
  int tid = threadIdx.x, wave = tid >> 6, lane = tid & 63;
  int quad = lane >> 4, l16 = lane & 15;
  int mb = blockIdx.x & 127;                // 128 m-blocks
  int sp = blockIdx.x >> 7;                 // 2 K-splits
  int row0 = mb * 64;
  int kbase = sp * (DIN / 2);
  int wm = wave >> 1, wn = wave & 1;        // wave tile 32m x 64n
  int f8 = l16 & 7;                         // swizzle key (row&7 == l16&7)

  const f32x4 zero = {0.f, 0.f, 0.f, 0.f};
  f32x4 acc[2][4];
#pragma unroll
  for (int i = 0; i < 2; i++)
#pragma unroll
    for (int j = 0; j < 4; j++) acc[i][j] = zero;

  for (int kt = 0; kt < (DIN / 2) / BK; ++kt) {   // 32 iters
    int k0 = kbase + kt * BK;
#pragma unroll
    for (int i = 0; i < 2; i++) {            // A tile: 64x64 = 512 chunks
      int c = i * 256 + tid;
      int r = c >> 3, kc = ((c & 7) ^ (r & 7)) * 8;
      async_copy16(&sA[c * 8], A + (int64_t)(row0 + r) * KC + k0 + kc);
    }
#pragma unroll
    for (int i = 0; i < 4; i++) {            // B tile: 128x64 = 1024 chunks
      int c = i * 256 + tid;
      int r = c >> 3, kc = ((c & 7) ^ (r & 7)) * 8;
      async_copy16(&sB[c * 8], Bb + (int64_t)r * DIN + k0 + kc);
    }
    __syncthreads();
#pragma unroll
    for (int ks = 0; ks < 2; ks++) {
      bf16x8 af[2], bfr[4];
      int qq = ks * 4 + quad;
      int qp = (qq ^ f8) * 8;                // physical quarter (ushort offset)
#pragma unroll
      for (int mi = 0; mi < 2; mi++)
        af[mi] = *(const bf16x8*)&sA[(wm * 32 + mi * 16 + l16) * BK + qp];
#pragma unroll
      for (int ni = 0; ni < 4; ni++)
        bfr[ni] = *(const bf16x8*)&sB[(wn * 64 + ni * 16 + l16) * BK + qp];
#pragma unroll
      for (int mi = 0; mi < 2; mi++)
#pragma unroll
        for (int ni = 0; ni < 4; ni++)
          acc[mi][ni] = __builtin_amdgcn_mfma_f32_16x16x32_bf16(af[mi], bfr[ni], acc[mi][ni], 0, 0, 0);
    }
    __syncthreads();
  }

  float* op = aout + (int64_t)sp * SEQ * 128;
#pragma unroll
  for (int ni = 0; ni < 4; ni++) {
    int er = wn * 64 + ni * 16 + l16;
#pragma unroll
    for (int mi = 0; mi < 2; mi++) {
      int s0 = row0 + wm * 32 + mi * 16 + quad * 4;
#pragma unroll
      for (int r = 0; r < 4; r++)
        op[(int64_t)(s0 + r) * 128 + er] = acc[mi][ni][r];
    }
  }
}

// sum splits, scale, mask, write bf16 LoRA columns of xcat
__global__ void lora_combine(const float* __restrict__ aout, const float* __restrict__ scal,
                             const int* __restrict__ tok, unsigned short* __restrict__ xcat) {
  int idx = blockIdx.x * 256 + threadIdx.x;   // s*128 + er, 1M total
  int s = idx >> 7, er = idx & 127;
  float v = aout[idx] + aout[idx + (int64_t)SEQ * 128];
  v *= scal[s];
  v = ((er >> 4) == tok[s]) ? v : 0.0f;
  xcat[(int64_t)s * KC + DIN + er] = f2bf(v);
}

// ---------------- main GEMM ----------------
// out[s][n] = sum_k xcat[s][k]*wcat[n][k] + bias[n], K=KC=4224.
// LDS XOR swizzle: slot (r, qp) holds gmem quarter qp ^ f(r), f(r)=(r+(r>>2))&3.
// 64B rows: bank group of lane i = (4i + phys_quarter) % 8 -> with this f all
// 8-lane b128 cycle-groups hit 8 distinct bank groups (conflict-free; was 4-way).
__global__ __launch_bounds__(256) void gemm_main(
    const unsigned short* __restrict__ A,   // xcat [SEQ][KC]
    const unsigned short* __restrict__ B,   // wcat [DOUT][KC]
    const float* __restrict__ bias,
    float* __restrict__ out) {
  constexpr int BK = 32;
  constexpr int KITERS = KC / BK;           // 132
  __shared__ unsigned short sA[128 * BK];
  __shared__ unsigned short sB[128 * BK];
  int tid = threadIdx.x, wave = tid >> 6, lane = tid & 63;
  int quad = lane >> 4, l16 = lane & 15;
  int bn = blockIdx.x & 31, bm = blockIdx.x >> 5;
  int row0 = bm * 128, col0 = bn * 128;
  int wm = wave >> 1, wn = wave & 1;        // 2x2 waves of 64x64
  int fR = (l16 + (l16 >> 2)) & 3;          // f(row) (row&15 == l16)
  int qp = (quad ^ fR) * 8;                 // physical quarter, ushort offset

  const f32x4 zero = {0.f, 0.f, 0.f, 0.f};
  f32x4 acc[4][4];
#pragma unroll
  for (int i = 0; i < 4; i++)
#pragma unroll
    for (int j = 0; j < 4; j++) acc[i][j] = zero;

  const unsigned short* Ab = A + (int64_t)row0 * KC;
  const unsigned short* Bb = B + (int64_t)col0 * KC;

  for (int kt = 0; kt < KITERS; ++kt) {
    int k0 = kt * BK;
#pragma unroll
    for (int i = 0; i < 2; i++) {           // 2x A + 2x B staging insts
      int c = i * 256 + tid;
      int r = c >> 2;
      int kc = ((c & 3) ^ ((r + (r >> 2)) & 3)) * 8;
      async_copy16(&sA[c * 8], Ab + (int64_t)r * KC + k0 + kc);
      async_copy16(&sB[c * 8], Bb + (int64_t)r * KC + k0 + kc);
    }
    __syncthreads();
    bf16x8 af[4], bfr[4];
#pragma unroll
    for (int mi = 0; mi < 4; mi++)
      af[mi] = *(const bf16x8*)&sA[(wm * 64 + mi * 16 + l16) * BK + qp];
#pragma unroll
    for (int ni = 0; ni < 4; ni++)
      bfr[ni] = *(const bf16x8*)&sB[(wn * 64 + ni * 16 + l16) * BK + qp];
#pragma unroll
    for (int mi = 0; mi < 4; mi++)
#pragma unroll
      for (int ni = 0; ni < 4; ni++)
        acc[mi][ni] = __builtin_amdgcn_mfma_f32_16x16x32_bf16(af[mi], bfr[ni], acc[mi][ni], 0, 0, 0);
    __syncthreads();
  }

#pragma unroll
  for (int ni = 0; ni < 4; ni++) {
    int col = col0 + wn * 64 + ni * 16 + l16;
    float bv = bias[col];
#pragma unroll
    for (int mi = 0; mi < 4; mi++) {
      int rbase = row0 + wm * 64 + mi * 16 + quad * 4;
#pragma unroll
      for (int r = 0; r < 4; r++)
        out[(int64_t)(rbase + r) * DOUT + col] = acc[mi][ni][r] + bv;
    }
  }
}

// ---------------- slow fp32 fallback (ws too small insurance) ----------------
__global__ void fb_aout(const float* __restrict__ x, const float* __restrict__ Abuf,
                        const float* __restrict__ scal, const int* __restrict__ tok,
                        float* __restrict__ aout) {
  int s = blockIdx.x;
  int e = tok[s];
  __shared__ float red[256];
  for (int r = 0; r < RANK; ++r) {
    float p = 0.f;
    for (int k = threadIdx.x; k < DIN; k += 256)
      p += x[(int64_t)s * DIN + k] * Abuf[((int64_t)e * RANK + r) * DIN + k];
    red[threadIdx.x] = p;
    __syncthreads();
    for (int off = 128; off > 0; off >>= 1) {
      if (threadIdx.x < off) red[threadIdx.x] += red[threadIdx.x + off];
      __syncthreads();
    }
    if (threadIdx.x == 0) aout[s * RANK + r] = red[0] * scal[s];
    __syncthreads();
  }
}
__global__ void fb_out(const float* __restrict__ x, const float* __restrict__ w,
                       const float* __restrict__ bias, const float* __restrict__ Bbuf,
                       const int* __restrict__ tok, const float* __restrict__ aout,
                       float* __restrict__ out) {
  int64_t idx = (int64_t)blockIdx.x * blockDim.x + threadIdx.x;
  int s = (int)(idx >> 12), n = (int)(idx & (DOUT - 1));
  float accv = bias[n];
  for (int k = 0; k < DIN; ++k)
    accv += x[(int64_t)s * DIN + k] * w[(int64_t)k * DOUT + n];
  int e = tok[s];
  float d = 0.f;
  for (int r = 0; r < RANK; ++r)
    d += aout[s * RANK + r] * Bbuf[((int64_t)e * DOUT + n) * RANK + r];
  out[idx] = accv + d;
}

extern "C" void kernel_launch(void* const* d_in, const int* in_sizes, int n_in,
                              void* d_out, int out_size, void* d_ws, size_t ws_size,
                              hipStream_t stream) {
  const float* x    = (const float*)d_in[0];
  const float* w    = (const float*)d_in[1];
  const float* bias = (const float*)d_in[2];
  const float* Abuf = (const float*)d_in[3];
  const float* Bbuf = (const float*)d_in[4];
  const float* scal = (const float*)d_in[5];
  const int*   tok  = (const int*)d_in[6];
  float* out = (float*)d_out;

  const size_t xcat_b = (size_t)SEQ * KC * 2;          // 69,206,016 B
  const size_t wcat_b = (size_t)DOUT * KC * 2;         // 34,603,008 B
  const size_t abf_b  = (size_t)NAD * RANK * DIN * 2;  //  1,048,576 B
  const size_t aout_b = (size_t)2 * SEQ * 128 * 4;     //  8,388,608 B

  if (ws_size >= xcat_b + wcat_b + abf_b + aout_b) {
    unsigned short* xcat = (unsigned short*)d_ws;
    unsigned short* wcat = (unsigned short*)((char*)d_ws + xcat_b);
    unsigned short* abf  = (unsigned short*)((char*)d_ws + xcat_b + wcat_b);
    float*          aout = (float*)((char*)d_ws + xcat_b + wcat_b + abf_b);
    cvt_x_kernel<<<4096, 256, 0, stream>>>(x, xcat);
    cvt_w_kernel<<<8192, 256, 0, stream>>>(w, wcat);
    cvt_b_kernel<<<(DOUT * 128) / 256, 256, 0, stream>>>(Bbuf, wcat);
    cvt_a_kernel<<<(NAD * RANK * DIN / 8) / 256, 256, 0, stream>>>(Abuf, abf);
    gemm_lora_a<<<256, 256, 0, stream>>>(xcat, abf, aout);
    lora_combine<<<(SEQ * 128) / 256, 256, 0, stream>>>(aout, scal, tok, xcat);
    gemm_main<<<(SEQ / 128) * (DOUT / 128), 256, 0, stream>>>(xcat, wcat, bias, out);
  } else {
    float* aout = (float*)d_ws;  // needs 512 KB
    fb_aout<<<SEQ, 256, 0, stream>>>(x, Abuf, scal, tok, aout);
    fb_out<<<(int)(((int64_t)SEQ * DOUT) / 256), 256, 0, stream>>>(x, w, bias, Bbuf, tok, aout, out);
  }
}